// Round 3
// baseline (788.503 us; speedup 1.0000x reference)
//
#include <hip/hip_runtime.h>
#include <cstdint>
#include <cstddef>

#define THRESH   0.5f
#define NEGPOS   3
#define VAR0     0.1f
#define VAR1     0.2f
#define MAXO     64
#define NPRI     8
#define A1_T     256
#define MINE_T   1024
#define MINE_W   (MINE_T / 64)
#define HCOPIES  8
#define POS_BLK  512
#define POS_T    256
#define NSLOT    64

// ---------------------------------------------------------------------------
// Kernel A1: per-(batch, prior-chunk) matching.
//  - per-prior best truth (strict > keeps first o  == jnp.argmax axis=0),
//    emitted as code u8 = (best_ov >= THRESH) ? idx+1 : 0
//  - per-truth best prior via u64 key (iou_bits<<32 | ~p): atomicMax picks
//    max iou, ties -> smallest p (== jnp.argmax axis=1 first-occurrence).
//  Pad priors (p >= P) have box=0,area=1 -> iou==0 and larger p, so they
//  lose every tie; their code is never stored.
// ---------------------------------------------------------------------------
__global__ __launch_bounds__(A1_T)
void match_kernel(const float* __restrict__ priors,
                  const float* __restrict__ targets,
                  unsigned char* __restrict__ code,
                  unsigned long long* __restrict__ g_bp,
                  int B, int P, int O, int chunks) {
    __shared__ float tx1[MAXO], ty1[MAXO], tx2[MAXO], ty2[MAXO], tarea[MAXO];
    const int b   = blockIdx.x / chunks;
    const int ch  = blockIdx.x % chunks;
    const int tid = threadIdx.x;

    if (tid < O) {
        const float* tr = targets + (size_t)(b * O + tid) * 5;
        float x1 = tr[0], y1 = tr[1], x2 = tr[2], y2 = tr[3];
        tx1[tid] = x1; ty1[tid] = y1; tx2[tid] = x2; ty2[tid] = y2;
        tarea[tid] = (x2 - x1) * (y2 - y1);
    }
    __syncthreads();

    float px1[NPRI], py1[NPRI], px2[NPRI], py2[NPRI], pa[NPRI], pov[NPRI];
    int   pidx[NPRI];
    const int p0 = ch * (A1_T * NPRI) + tid;
#pragma unroll
    for (int i = 0; i < NPRI; ++i) {
        int p = p0 + i * A1_T;
        pov[i] = -1.0f; pidx[i] = 0;
        px1[i] = 0.f; py1[i] = 0.f; px2[i] = 0.f; py2[i] = 0.f; pa[i] = 1.0f;
        if (p < P) {
            float4 pr = *(const float4*)(priors + (size_t)p * 4);
            px1[i] = pr.x - pr.z * 0.5f; py1[i] = pr.y - pr.w * 0.5f;
            px2[i] = pr.x + pr.z * 0.5f; py2[i] = pr.y + pr.w * 0.5f;
            pa[i]  = pr.z * pr.w;
        }
    }

    const int lane = tid & 63;
    for (int o = 0; o < O; ++o) {
        float ax1 = tx1[o], ay1 = ty1[o], ax2 = tx2[o], ay2 = ty2[o], aa = tarea[o];
        float bo = -1.0f; unsigned bp = 0u;
#pragma unroll
        for (int i = 0; i < NPRI; ++i) {
            float lx = fmaxf(ax1, px1[i]), ly = fmaxf(ay1, py1[i]);
            float rx = fminf(ax2, px2[i]), ry = fminf(ay2, py2[i]);
            float w = fmaxf(rx - lx, 0.0f), h = fmaxf(ry - ly, 0.0f);
            float inter = w * h;
            float iou = __fdividef(inter, aa + pa[i] - inter);
            if (iou > pov[i]) { pov[i] = iou; pidx[i] = o; }      // first o wins
            if (iou > bo)     { bo = iou; bp = (unsigned)(p0 + i * A1_T); }
        }
        unsigned long long key =
            ((unsigned long long)__float_as_uint(bo) << 32) |
            (unsigned long long)(0xFFFFFFFFu - bp);
#pragma unroll
        for (int d = 1; d < 64; d <<= 1) {
            unsigned long long other = __shfl_xor(key, d, 64);
            if (other > key) key = other;
        }
        if (lane == 0)
            atomicMax(&g_bp[(size_t)b * O + o], key);
    }

#pragma unroll
    for (int i = 0; i < NPRI; ++i) {
        int p = p0 + i * A1_T;
        if (p < P)
            code[(size_t)b * P + p] =
                (pov[i] >= THRESH) ? (unsigned char)(pidx[i] + 1) : (unsigned char)0;
    }
}

// ---------------------------------------------------------------------------
// Kernel A2: forced-match patch. Serial per batch => last truth wins on
// duplicate best_prior_idx (matches sequential .at[].set). Forced entries
// are indistinguishable from natural positives downstream (ov=2.0>=THRESH).
// ---------------------------------------------------------------------------
__global__ void force_kernel(const unsigned long long* __restrict__ g_bp,
                             unsigned char* __restrict__ code,
                             int B, int P, int O) {
    int b = blockIdx.x * blockDim.x + threadIdx.x;
    if (b >= B) return;
    for (int o = 0; o < O; ++o) {
        unsigned long long key = g_bp[(size_t)b * O + o];
        unsigned p = 0xFFFFFFFFu - (unsigned)(key & 0xFFFFFFFFull);
        code[(size_t)b * P + p] = (unsigned char)(o + 1);
    }
}

// ---------------------------------------------------------------------------
// Kernel B: streaming negative pass + positive compaction.
//   negatives: mce = LSE2(obj) - obj0   (== ce_c == ce_o, mined once)
//   positives: mce = 0, appended (ballot-compacted, 1 atomic/wave) to list
//              entry u64 = (t<<32)|(p<<16)|(b*O+o); npos counted per row.
// No divergence heavier than the 2-exp LSE2; fully coalesced.
// ---------------------------------------------------------------------------
__global__ __launch_bounds__(256)
void ce_kernel(const float* __restrict__ obj,
               const unsigned char* __restrict__ code,
               float* __restrict__ mce,
               unsigned long long* __restrict__ list,
               unsigned* __restrict__ g_cnt,
               float* __restrict__ rowacc,
               int B, int P, int O) {
    const int b = blockIdx.y;
    const int p = blockIdx.x * 256 + threadIdx.x;
    const int tid = threadIdx.x, wv = tid >> 6, lane = tid & 63;

    bool pos = false;
    unsigned cc = 0;
    size_t t = (size_t)b * P + p;
    if (p < P) {
        cc = code[t];
        float2 ob = *(const float2*)(obj + t * 2);
        float m    = fmaxf(ob.x, ob.y);
        float lse2 = m + __logf(__expf(ob.x - m) + __expf(ob.y - m));
        if (cc == 0) {
            mce[t] = lse2 - ob.x;
        } else {
            mce[t] = 0.0f;
            pos = true;
        }
    }

    unsigned long long msk = __ballot(pos);
    __shared__ unsigned s_cnt[4];
    int cnt = __popcll(msk);
    if (msk != 0ull) {
        int leader = __ffsll((unsigned long long)msk) - 1;
        unsigned base = 0;
        if (lane == leader) base = atomicAdd(g_cnt, (unsigned)cnt);
        base = (unsigned)__shfl((int)base, leader, 64);
        if (pos) {
            unsigned off = base + (unsigned)__popcll(msk & ((1ull << lane) - 1ull));
            unsigned long long e = ((unsigned long long)(unsigned)t << 32) |
                                   ((unsigned long long)(unsigned)p << 16) |
                                   (unsigned long long)(unsigned)(b * O + (int)cc - 1);
            list[off] = e;
        }
    }
    if (lane == 0) s_cnt[wv] = (unsigned)cnt;
    __syncthreads();
    if (tid == 0) {
        unsigned total = s_cnt[0] + s_cnt[1] + s_cnt[2] + s_cnt[3];
        if (total) atomicAdd(rowacc + (size_t)b * 16, (float)total);
    }
}

// ---------------------------------------------------------------------------
// Kernel B2: positive pass. One quarter-wave (16 lanes) per positive:
// coalesced conf-row LSE + shuffle reduce; lq==0 does the scalar epilogue
// (ce_c, ce_o, smooth-L1). Block-reduced, atomics spread over 64 slots.
// ---------------------------------------------------------------------------
__global__ __launch_bounds__(POS_T)
void pos_kernel(const float* __restrict__ loc, const float* __restrict__ conf,
                const float* __restrict__ obj, const float* __restrict__ priors,
                const float* __restrict__ targets,
                const unsigned long long* __restrict__ list,
                const unsigned* __restrict__ g_cnt,
                float* __restrict__ g_acc, int C) {
    const unsigned cnt = *g_cnt;
    const int tid  = threadIdx.x;
    const int lane = tid & 63, wv = tid >> 6;
    const int q    = lane >> 4, lq = lane & 15;
    const unsigned gw   = (blockIdx.x * POS_T + tid) >> 6;
    const unsigned Wtot = (gridDim.x * POS_T) >> 6;

    float sl = 0.f, cec = 0.f, ceo = 0.f;

    for (unsigned base = gw * 4; base < cnt; base += Wtot * 4) {
        unsigned e = base + (unsigned)q;
        bool act = e < cnt;
        unsigned long long v = act ? list[e] : 0ull;
        unsigned t  = (unsigned)(v >> 32);
        unsigned p  = (unsigned)(v >> 16) & 0xFFFFu;
        unsigned to = (unsigned)v & 0xFFFFu;
        const float* cr = conf + (size_t)t * C;

        float s = 0.f;
        if (act)
            for (int j = lq; j < C; j += 16) s += __expf(cr[j]);
#pragma unroll
        for (int d = 1; d < 16; d <<= 1) s += __shfl_xor(s, d, 16);

        if (act && lq == 0) {
            const float* tr = targets + (size_t)to * 5;
            float2 ob = *(const float2*)(obj + (size_t)t * 2);
            float4 pr = *(const float4*)(priors + (size_t)p * 4);
            float4 ld = *(const float4*)(loc + (size_t)t * 4);
            float mx1 = tr[0], my1 = tr[1], mx2 = tr[2], my2 = tr[3];
            int   lbl = (int)tr[4];

            float m    = fmaxf(ob.x, ob.y);
            float lse2 = m + __logf(__expf(ob.x - m) + __expf(ob.y - m));
            float lsec = __logf(s);
            cec += lsec + lse2 - ob.y - cr[lbl];
            ceo += lse2 - ob.y;

            float gx = ((mx1 + mx2) * 0.5f - pr.x) / (VAR0 * pr.z);
            float gy = ((my1 + my2) * 0.5f - pr.y) / (VAR0 * pr.w);
            float gw2 = __logf((mx2 - mx1) / pr.z) / VAR1;
            float gh  = __logf((my2 - my1) / pr.w) / VAR1;
            float d0 = ld.x - gx,  a0 = fabsf(d0); sl += (a0 < 1.f) ? 0.5f * d0 * d0 : a0 - 0.5f;
            float d1 = ld.y - gy,  a1 = fabsf(d1); sl += (a1 < 1.f) ? 0.5f * d1 * d1 : a1 - 0.5f;
            float d2 = ld.z - gw2, a2 = fabsf(d2); sl += (a2 < 1.f) ? 0.5f * d2 * d2 : a2 - 0.5f;
            float d3 = ld.w - gh,  a3 = fabsf(d3); sl += (a3 < 1.f) ? 0.5f * d3 * d3 : a3 - 0.5f;
        }
    }

    __shared__ float red[POS_T / 64][3];
#pragma unroll
    for (int d = 32; d > 0; d >>= 1) {
        sl  += __shfl_down(sl,  d, 64);
        cec += __shfl_down(cec, d, 64);
        ceo += __shfl_down(ceo, d, 64);
    }
    if (lane == 0) { red[wv][0] = sl; red[wv][1] = cec; red[wv][2] = ceo; }
    __syncthreads();
    if (tid < 3) {
        float vv = red[0][tid] + red[1][tid] + red[2][tid] + red[3][tid];
        if (vv != 0.0f)
            atomicAdd(g_acc + (size_t)(blockIdx.x & (NSLOT - 1)) * 16 + tid, vv);
    }
}

// ---------------------------------------------------------------------------
// Kernel C: per-row radix-select top-k sum of mined losses (k = min(3*npos,
// P-1)); values > 0, IEEE bits order == float order. Top-k sum ==
// sum(v > v_k) + (k - cnt_gt) * v_k. Same sum feeds loss_c and loss_obj.
// ---------------------------------------------------------------------------
__global__ __launch_bounds__(MINE_T)
void mine_kernel(const float* __restrict__ mce, const float* __restrict__ rowacc,
                 float* __restrict__ g_neg, int P) {
    const int b = blockIdx.x;
    const float* row = mce + (size_t)b * P;
    int npos = (int)rowacc[(size_t)b * 16];
    int k = NEGPOS * npos;
    if (k > P - 1) k = P - 1;
    if (k <= 0) return;

    __shared__ unsigned hist[HCOPIES][257];
    __shared__ unsigned s_prefix;
    __shared__ int      s_rem;
    __shared__ float    s_ws[MINE_W];
    __shared__ int      s_wc[MINE_W];

    const int tid  = threadIdx.x;
    const int wv   = tid >> 6;
    const int hc   = wv & (HCOPIES - 1);
    const int lane = tid & 63;

    unsigned prefix = 0u;
    int rem = k;
    for (int shift = 24; shift >= 0; shift -= 8) {
        for (int i = tid; i < HCOPIES * 257; i += MINE_T) (&hist[0][0])[i] = 0u;
        __syncthreads();
        unsigned himask = (shift == 24) ? 0u : (0xFFFFFFFFu << (shift + 8));
        for (int i = tid; i < P; i += MINE_T) {
            unsigned bits = __float_as_uint(row[i]);
            if ((bits & himask) == prefix)
                atomicAdd(&hist[hc][(bits >> shift) & 0xFFu], 1u);
        }
        __syncthreads();
        if (tid == 0) {
            int cum = 0; unsigned bin = 0;
            for (int bb = 255; bb >= 0; --bb) {
                int cnt = 0;
#pragma unroll
                for (int h = 0; h < HCOPIES; ++h) cnt += (int)hist[h][bb];
                if (cum + cnt >= rem) { bin = (unsigned)bb; rem -= cum; break; }
                cum += cnt;
            }
            s_prefix = prefix | (bin << shift);
            s_rem = rem;
        }
        __syncthreads();
        prefix = s_prefix;
        rem    = s_rem;
    }

    float vk = __uint_as_float(prefix);
    float s = 0.f; int cnt = 0;
    for (int i = tid; i < P; i += MINE_T) {
        float v = row[i];
        if (__float_as_uint(v) > prefix) { s += v; ++cnt; }
    }
#pragma unroll
    for (int d = 32; d > 0; d >>= 1) {
        s   += __shfl_down(s, d, 64);
        cnt += __shfl_down(cnt, d, 64);
    }
    if (lane == 0) { s_ws[wv] = s; s_wc[wv] = cnt; }
    __syncthreads();
    if (tid == 0) {
        float st = 0.f; int ct = 0;
        for (int w = 0; w < MINE_W; ++w) { st += s_ws[w]; ct += s_wc[w]; }
        atomicAdd(g_neg, st + (float)(k - ct) * vk);
    }
}

// ---------------------------------------------------------------------------
// Kernel D: final combine + divide by N. One wave.
// ---------------------------------------------------------------------------
__global__ void finish_kernel(const float* __restrict__ rowacc,
                              const float* __restrict__ g_acc,
                              const float* __restrict__ g_neg,
                              float* __restrict__ out, int B) {
    int lane = threadIdx.x;
    float npos = 0.f;
    for (int b = lane; b < B; b += 64) npos += rowacc[(size_t)b * 16];
    float sl  = g_acc[(size_t)lane * 16 + 0];
    float cec = g_acc[(size_t)lane * 16 + 1];
    float ceo = g_acc[(size_t)lane * 16 + 2];
#pragma unroll
    for (int d = 32; d > 0; d >>= 1) {
        npos += __shfl_down(npos, d, 64);
        sl   += __shfl_down(sl,   d, 64);
        cec  += __shfl_down(cec,  d, 64);
        ceo  += __shfl_down(ceo,  d, 64);
    }
    if (lane == 0) {
        float neg = *g_neg;
        out[0] = sl / npos;
        out[1] = (cec + neg) / npos;
        out[2] = (ceo + neg) / npos;
    }
}

extern "C" void kernel_launch(void* const* d_in, const int* in_sizes, int n_in,
                              void* d_out, int out_size, void* d_ws, size_t ws_size,
                              hipStream_t stream) {
    const float* loc     = (const float*)d_in[0];
    const float* conf    = (const float*)d_in[1];
    const float* obj     = (const float*)d_in[2];
    const float* priors  = (const float*)d_in[3];
    const float* targets = (const float*)d_in[4];

    const int P = in_sizes[3] / 4;
    const int B = in_sizes[0] / (4 * P);
    const int C = in_sizes[1] / (B * P);
    const int O = in_sizes[4] / (5 * B);

    char* ws = (char*)d_ws;
    size_t off = 0;
    unsigned* g_cnt = (unsigned*)(ws + off);       off += 16;
    float*    g_neg = (float*)(ws + off);          off += 16;
    off = (off + 63) & ~(size_t)63;
    float* rowacc = (float*)(ws + off);            off += (size_t)B * 16 * sizeof(float);
    float* g_acc  = (float*)(ws + off);            off += (size_t)NSLOT * 16 * sizeof(float);
    unsigned long long* g_bp = (unsigned long long*)(ws + off);
    off += (size_t)B * O * sizeof(unsigned long long);
    const size_t zero_bytes = off;
    off = (off + 127) & ~(size_t)127;
    unsigned char* code = (unsigned char*)(ws + off); off += (size_t)B * P;
    off = (off + 127) & ~(size_t)127;
    float* mce = (float*)(ws + off);               off += (size_t)B * P * sizeof(float);
    off = (off + 127) & ~(size_t)127;
    unsigned long long* list = (unsigned long long*)(ws + off);
    off += (size_t)B * P * sizeof(unsigned long long);

    hipMemsetAsync(d_ws, 0, zero_bytes, stream);

    const int chunks = (P + A1_T * NPRI - 1) / (A1_T * NPRI);
    match_kernel<<<B * chunks, A1_T, 0, stream>>>(priors, targets, code, g_bp,
                                                  B, P, O, chunks);
    force_kernel<<<(B + 63) / 64, 64, 0, stream>>>(g_bp, code, B, P, O);
    dim3 ce_grid((P + 255) / 256, B);
    ce_kernel<<<ce_grid, 256, 0, stream>>>(obj, code, mce, list, g_cnt, rowacc,
                                           B, P, O);
    pos_kernel<<<POS_BLK, POS_T, 0, stream>>>(loc, conf, obj, priors, targets,
                                              list, g_cnt, g_acc, C);
    mine_kernel<<<B, MINE_T, 0, stream>>>(mce, rowacc, g_neg, P);
    finish_kernel<<<1, 64, 0, stream>>>(rowacc, g_acc, g_neg, (float*)d_out, B);
}

// Round 4
// 585.581 us; speedup vs baseline: 1.3465x; 1.3465x over previous
//
#include <hip/hip_runtime.h>
#include <cstdint>
#include <cstddef>

#define THRESH   0.5f
#define NEGPOS   3
#define VAR0     0.1f
#define VAR1     0.2f
#define MAXO     64
#define NPRI     8
#define A1_T     256
#define MINE_T   1024
#define MINE_W   (MINE_T / 64)
#define HCOPIES  8

// ---------------------------------------------------------------------------
// Kernel A1: per-(batch, prior-chunk) matching.
//  - per-prior best truth (strict > keeps first o  == jnp.argmax axis=0),
//    emitted as code u8 = (best_ov >= THRESH) ? idx+1 : 0
//  - per-truth best prior via u64 key (iou_bits<<32 | ~p): atomicMax picks
//    max iou, ties -> smallest p (== jnp.argmax axis=1 first-occurrence).
//  Pad priors (p >= P) have box=0,area=1 -> iou==0 and larger p, so they
//  lose every tie; their code is never stored.
// ---------------------------------------------------------------------------
__global__ __launch_bounds__(A1_T)
void match_kernel(const float* __restrict__ priors,
                  const float* __restrict__ targets,
                  unsigned char* __restrict__ code,
                  unsigned long long* __restrict__ g_bp,
                  int B, int P, int O, int chunks) {
    __shared__ float tx1[MAXO], ty1[MAXO], tx2[MAXO], ty2[MAXO], tarea[MAXO];
    const int b   = blockIdx.x / chunks;
    const int ch  = blockIdx.x % chunks;
    const int tid = threadIdx.x;

    if (tid < O) {
        const float* tr = targets + (size_t)(b * O + tid) * 5;
        float x1 = tr[0], y1 = tr[1], x2 = tr[2], y2 = tr[3];
        tx1[tid] = x1; ty1[tid] = y1; tx2[tid] = x2; ty2[tid] = y2;
        tarea[tid] = (x2 - x1) * (y2 - y1);
    }
    __syncthreads();

    float px1[NPRI], py1[NPRI], px2[NPRI], py2[NPRI], pa[NPRI], pov[NPRI];
    int   pidx[NPRI];
    const int p0 = ch * (A1_T * NPRI) + tid;
#pragma unroll
    for (int i = 0; i < NPRI; ++i) {
        int p = p0 + i * A1_T;
        pov[i] = -1.0f; pidx[i] = 0;
        px1[i] = 0.f; py1[i] = 0.f; px2[i] = 0.f; py2[i] = 0.f; pa[i] = 1.0f;
        if (p < P) {
            float4 pr = *(const float4*)(priors + (size_t)p * 4);
            px1[i] = pr.x - pr.z * 0.5f; py1[i] = pr.y - pr.w * 0.5f;
            px2[i] = pr.x + pr.z * 0.5f; py2[i] = pr.y + pr.w * 0.5f;
            pa[i]  = pr.z * pr.w;
        }
    }

    const int lane = tid & 63;
    for (int o = 0; o < O; ++o) {
        float ax1 = tx1[o], ay1 = ty1[o], ax2 = tx2[o], ay2 = ty2[o], aa = tarea[o];
        float bo = -1.0f; unsigned bp = 0u;
#pragma unroll
        for (int i = 0; i < NPRI; ++i) {
            float lx = fmaxf(ax1, px1[i]), ly = fmaxf(ay1, py1[i]);
            float rx = fminf(ax2, px2[i]), ry = fminf(ay2, py2[i]);
            float w = fmaxf(rx - lx, 0.0f), h = fmaxf(ry - ly, 0.0f);
            float inter = w * h;
            float iou = __fdividef(inter, aa + pa[i] - inter);
            if (iou > pov[i]) { pov[i] = iou; pidx[i] = o; }      // first o wins
            if (iou > bo)     { bo = iou; bp = (unsigned)(p0 + i * A1_T); }
        }
        unsigned long long key =
            ((unsigned long long)__float_as_uint(bo) << 32) |
            (unsigned long long)(0xFFFFFFFFu - bp);
#pragma unroll
        for (int d = 1; d < 64; d <<= 1) {
            unsigned long long other = __shfl_xor(key, d, 64);
            if (other > key) key = other;
        }
        if (lane == 0)
            atomicMax(&g_bp[(size_t)b * O + o], key);
    }

#pragma unroll
    for (int i = 0; i < NPRI; ++i) {
        int p = p0 + i * A1_T;
        if (p < P)
            code[(size_t)b * P + p] =
                (pov[i] >= THRESH) ? (unsigned char)(pidx[i] + 1) : (unsigned char)0;
    }
}

// ---------------------------------------------------------------------------
// Kernel A2: forced-match patch. Serial per batch => last truth wins on
// duplicate best_prior_idx (matches sequential .at[].set). Forced entries
// are indistinguishable from natural positives downstream (ov=2.0>=THRESH).
// ---------------------------------------------------------------------------
__global__ void force_kernel(const unsigned long long* __restrict__ g_bp,
                             unsigned char* __restrict__ code,
                             int B, int P, int O) {
    int b = blockIdx.x * blockDim.x + threadIdx.x;
    if (b >= B) return;
    for (int o = 0; o < O; ++o) {
        unsigned long long key = g_bp[(size_t)b * O + o];
        unsigned p = 0xFFFFFFFFu - (unsigned)(key & 0xFFFFFFFFull);
        code[(size_t)b * P + p] = (unsigned char)(o + 1);
    }
}

// ---------------------------------------------------------------------------
// Kernel B (fused): streaming negative pass + wave-cooperative positives.
//   negatives: mce = LSE2(obj) - obj0   (== ce_c == ce_o, mined once)
//   positives: wave-uniform loop over the ballot's set bits; all 64 lanes
//     cooperatively exp-sum the 81-wide conf row (coalesced), butterfly-
//     reduce, deposit S into the owning lane; then every positive lane runs
//     its epilogue (ce_c, ce_o, smooth-L1) in parallel.
// NO global compaction / NO same-line global atomics (the R3 regression:
// 16k per-wave atomicAdd-with-return on one g_cnt line cost ~190 us).
// Block-reduced partials -> 4 atomics/block onto per-row 64B rowacc lines.
// ---------------------------------------------------------------------------
__global__ __launch_bounds__(256)
void ce_pos_kernel(const float* __restrict__ loc, const float* __restrict__ conf,
                   const float* __restrict__ obj, const float* __restrict__ priors,
                   const float* __restrict__ targets,
                   const unsigned char* __restrict__ code,
                   float* __restrict__ mce, float* __restrict__ rowacc,
                   int B, int P, int C, int O) {
    const int b = blockIdx.y;
    const int p = blockIdx.x * 256 + threadIdx.x;
    const int tid = threadIdx.x, wv = tid >> 6, lane = tid & 63;

    bool pos = false;
    unsigned cc = 0;
    const unsigned t = (unsigned)(b * P + p);
    float obx = 0.f, oby = 0.f, lse2 = 0.f;
    if (p < P) {
        cc = code[t];
        float2 ob = *(const float2*)(obj + (size_t)t * 2);
        obx = ob.x; oby = ob.y;
        float m = fmaxf(obx, oby);
        lse2 = m + __logf(__expf(obx - m) + __expf(oby - m));
        if (cc == 0) {
            mce[t] = lse2 - obx;         // negative: ce_c == ce_o, mined once
        } else {
            mce[t] = 0.0f;               // positive: zeroed for mining
            pos = true;
        }
    }

    // wave-cooperative conf-row LSE for each positive lane
    const unsigned long long msk = __ballot(pos);
    float myS = 0.f;
    unsigned long long rem = msk;
    while (rem) {
        const int src = __ffsll(rem) - 1;
        rem &= rem - 1;
        const unsigned t_s = (unsigned)__shfl((int)t, src, 64);
        const float* cr = conf + (size_t)t_s * C;
        float s = 0.f;
        for (int j = lane; j < C; j += 64) s += __expf(cr[j]);
#pragma unroll
        for (int d = 1; d < 64; d <<= 1) s += __shfl_xor(s, d, 64);
        if (lane == src) myS = s;
    }

    // parallel epilogue on positive lanes
    float sl = 0.f, cec = 0.f, ceo = 0.f;
    if (pos) {
        const float* cr = conf + (size_t)t * C;
        const float* tr = targets + (size_t)((unsigned)(b * O) + cc - 1u) * 5;
        float4 pr = *(const float4*)(priors + (size_t)p * 4);
        float4 ld = *(const float4*)(loc + (size_t)t * 4);
        float mx1 = tr[0], my1 = tr[1], mx2 = tr[2], my2 = tr[3];
        int   lbl = (int)tr[4];

        float lsec = __logf(myS);
        cec = lsec + lse2 - oby - cr[lbl];
        ceo = lse2 - oby;

        float gx  = ((mx1 + mx2) * 0.5f - pr.x) / (VAR0 * pr.z);
        float gy  = ((my1 + my2) * 0.5f - pr.y) / (VAR0 * pr.w);
        float gw2 = __logf((mx2 - mx1) / pr.z) / VAR1;
        float gh  = __logf((my2 - my1) / pr.w) / VAR1;
        float d0 = ld.x - gx,  a0 = fabsf(d0); sl += (a0 < 1.f) ? 0.5f * d0 * d0 : a0 - 0.5f;
        float d1 = ld.y - gy,  a1 = fabsf(d1); sl += (a1 < 1.f) ? 0.5f * d1 * d1 : a1 - 0.5f;
        float d2 = ld.z - gw2, a2 = fabsf(d2); sl += (a2 < 1.f) ? 0.5f * d2 * d2 : a2 - 0.5f;
        float d3 = ld.w - gh,  a3 = fabsf(d3); sl += (a3 < 1.f) ? 0.5f * d3 * d3 : a3 - 0.5f;
    }

    // block reduction -> 4 atomics per block on this row's private 64B line
    float cntp = (float)__popcll(msk);   // wave-uniform; counted once per wave below
    __shared__ float red[4][4];
#pragma unroll
    for (int d = 32; d > 0; d >>= 1) {
        sl  += __shfl_down(sl,  d, 64);
        cec += __shfl_down(cec, d, 64);
        ceo += __shfl_down(ceo, d, 64);
    }
    if (lane == 0) {
        red[wv][0] = cntp; red[wv][1] = sl; red[wv][2] = cec; red[wv][3] = ceo;
    }
    __syncthreads();
    if (tid < 4) {
        float v = red[0][tid] + red[1][tid] + red[2][tid] + red[3][tid];
        if (v != 0.0f)
            atomicAdd(rowacc + (size_t)b * 16 + tid, v);
    }
}

// ---------------------------------------------------------------------------
// Kernel C: per-row radix-select top-k sum of mined losses (k = min(3*npos,
// P-1)); values > 0, IEEE bits order == float order. Top-k sum ==
// sum(v > v_k) + (k - cnt_gt) * v_k. Same sum feeds loss_c and loss_obj.
// ---------------------------------------------------------------------------
__global__ __launch_bounds__(MINE_T)
void mine_kernel(const float* __restrict__ mce, const float* __restrict__ rowacc,
                 float* __restrict__ g_neg, int P) {
    const int b = blockIdx.x;
    const float* row = mce + (size_t)b * P;
    int npos = (int)rowacc[(size_t)b * 16];
    int k = NEGPOS * npos;
    if (k > P - 1) k = P - 1;
    if (k <= 0) return;

    __shared__ unsigned hist[HCOPIES][257];
    __shared__ unsigned s_prefix;
    __shared__ int      s_rem;
    __shared__ float    s_ws[MINE_W];
    __shared__ int      s_wc[MINE_W];

    const int tid  = threadIdx.x;
    const int wv   = tid >> 6;
    const int hc   = wv & (HCOPIES - 1);
    const int lane = tid & 63;

    unsigned prefix = 0u;
    int rem = k;
    for (int shift = 24; shift >= 0; shift -= 8) {
        for (int i = tid; i < HCOPIES * 257; i += MINE_T) (&hist[0][0])[i] = 0u;
        __syncthreads();
        unsigned himask = (shift == 24) ? 0u : (0xFFFFFFFFu << (shift + 8));
        for (int i = tid; i < P; i += MINE_T) {
            unsigned bits = __float_as_uint(row[i]);
            if ((bits & himask) == prefix)
                atomicAdd(&hist[hc][(bits >> shift) & 0xFFu], 1u);
        }
        __syncthreads();
        if (tid == 0) {
            int cum = 0; unsigned bin = 0;
            for (int bb = 255; bb >= 0; --bb) {
                int cnt = 0;
#pragma unroll
                for (int h = 0; h < HCOPIES; ++h) cnt += (int)hist[h][bb];
                if (cum + cnt >= rem) { bin = (unsigned)bb; rem -= cum; break; }
                cum += cnt;
            }
            s_prefix = prefix | (bin << shift);
            s_rem = rem;
        }
        __syncthreads();
        prefix = s_prefix;
        rem    = s_rem;
    }

    float vk = __uint_as_float(prefix);
    float s = 0.f; int cnt = 0;
    for (int i = tid; i < P; i += MINE_T) {
        float v = row[i];
        if (__float_as_uint(v) > prefix) { s += v; ++cnt; }
    }
#pragma unroll
    for (int d = 32; d > 0; d >>= 1) {
        s   += __shfl_down(s, d, 64);
        cnt += __shfl_down(cnt, d, 64);
    }
    if (lane == 0) { s_ws[wv] = s; s_wc[wv] = cnt; }
    __syncthreads();
    if (tid == 0) {
        float st = 0.f; int ct = 0;
        for (int w = 0; w < MINE_W; ++w) { st += s_ws[w]; ct += s_wc[w]; }
        atomicAdd(g_neg, st + (float)(k - ct) * vk);
    }
}

// ---------------------------------------------------------------------------
// Kernel D: final combine + divide by N. One wave.
// ---------------------------------------------------------------------------
__global__ void finish_kernel(const float* __restrict__ rowacc,
                              const float* __restrict__ g_neg,
                              float* __restrict__ out, int B) {
    const int lane = threadIdx.x;
    float npos = 0.f, sl = 0.f, cec = 0.f, ceo = 0.f;
    for (int b = lane; b < B; b += 64) {
        float4 v = *(const float4*)(rowacc + (size_t)b * 16);
        npos += v.x; sl += v.y; cec += v.z; ceo += v.w;
    }
#pragma unroll
    for (int d = 32; d > 0; d >>= 1) {
        npos += __shfl_down(npos, d, 64);
        sl   += __shfl_down(sl,   d, 64);
        cec  += __shfl_down(cec,  d, 64);
        ceo  += __shfl_down(ceo,  d, 64);
    }
    if (lane == 0) {
        float neg = *g_neg;
        out[0] = sl / npos;
        out[1] = (cec + neg) / npos;
        out[2] = (ceo + neg) / npos;
    }
}

extern "C" void kernel_launch(void* const* d_in, const int* in_sizes, int n_in,
                              void* d_out, int out_size, void* d_ws, size_t ws_size,
                              hipStream_t stream) {
    const float* loc     = (const float*)d_in[0];
    const float* conf    = (const float*)d_in[1];
    const float* obj     = (const float*)d_in[2];
    const float* priors  = (const float*)d_in[3];
    const float* targets = (const float*)d_in[4];

    const int P = in_sizes[3] / 4;
    const int B = in_sizes[0] / (4 * P);
    const int C = in_sizes[1] / (B * P);
    const int O = in_sizes[4] / (5 * B);

    char* ws = (char*)d_ws;
    size_t off = 0;
    float* g_neg = (float*)(ws + off);             off += 64;
    float* rowacc = (float*)(ws + off);            off += (size_t)B * 16 * sizeof(float);
    unsigned long long* g_bp = (unsigned long long*)(ws + off);
    off += (size_t)B * O * sizeof(unsigned long long);
    const size_t zero_bytes = off;
    off = (off + 127) & ~(size_t)127;
    unsigned char* code = (unsigned char*)(ws + off); off += (size_t)B * P;
    off = (off + 127) & ~(size_t)127;
    float* mce = (float*)(ws + off);               off += (size_t)B * P * sizeof(float);

    hipMemsetAsync(d_ws, 0, zero_bytes, stream);

    const int chunks = (P + A1_T * NPRI - 1) / (A1_T * NPRI);
    match_kernel<<<B * chunks, A1_T, 0, stream>>>(priors, targets, code, g_bp,
                                                  B, P, O, chunks);
    force_kernel<<<(B + 63) / 64, 64, 0, stream>>>(g_bp, code, B, P, O);
    dim3 ce_grid((P + 255) / 256, B);
    ce_pos_kernel<<<ce_grid, 256, 0, stream>>>(loc, conf, obj, priors, targets,
                                               code, mce, rowacc, B, P, C, O);
    mine_kernel<<<B, MINE_T, 0, stream>>>(mce, rowacc, g_neg, P);
    finish_kernel<<<1, 64, 0, stream>>>(rowacc, g_neg, (float*)d_out, B);
}